// Round 4
// baseline (521.400 us; speedup 1.0000x reference)
//
#include <hip/hip_runtime.h>
#include <hip/hip_cooperative_groups.h>

namespace cg = cooperative_groups;

typedef float v4f __attribute__((ext_vector_type(4)));

#define NB 8        // batch
#define NL 24       // layers
#define NR 64       // chunks
#define ND 4096     // DL
#define NFUSED 1536
#define NTF 1024
#define NPF 512
#define KP 4096     // DP

// split-K chunking
#define TKC 144     // tfeat k-chunks of 128
#define PKC 32      // pfeat k-chunks of 128
#define FKC 12      // F k-chunks of 128

// workspace float offsets
#define WS_FUSED 0          // 12288
#define WS_GATE  12288      // 192                -> 12480
#define WS_PLA   12480      // 2*24*4096 = 196608 -> 209088
#define WS_PLB   209088     // 196608             -> 405696
#define WS_CA    405696     // 262144             -> 667840
#define WS_CBT   667840     // 262144             -> 929984
#define WS_PT    929984     // 144*8*1024=1179648 -> 2109632
#define WS_PP    2109632    // 32*8*512 = 131072  -> 2240704
#define WS_PFA   2240704    // 12*8*4096= 393216  -> 2633920
#define WS_PFB   2633920    // 393216             -> 3027136

struct KParams {
  const float *As, *Bs, *prompt, *W_ct, *b_ct, *W_cp, *b_cp, *W_pc, *b_pc,
              *E_layer, *E_chunk, *W_A, *b_A, *W_B, *b_B;
  float *fused, *gatew, *pLA, *pLB, *CA, *CBT, *partT, *partP, *pFA, *pFB;
  float *outA, *outB, *outG;
};

// One cooperative kernel, 4 phases, 3 grid syncs.
__global__ __launch_bounds__(256, 4) void k_all(KParams p) {
  cg::grid_group grid = cg::this_grid();
  const int bid = blockIdx.x;
  const int tid = threadIdx.x;
  const int G = gridDim.x;
  __shared__ float smem[4096];   // e (4096) / red (256) / sbase (512)

  // ---------------- Phase 1: fused-independent partials (736 units) -----
  for (int u = bid; u < 736; u += G) {
    if (u < 576) {                      // tfeat partial (k-chunk 128)
      const int j = (u & 3) * 256 + tid;
      const int kc = u >> 2;
      const int kbase = kc * 128;
      float acc[NB] = {};
      for (int kk = 0; kk < 128; ++kk) {
        const int k = kbase + kk;
        const float w = p.W_ct[(size_t)k * NTF + j];
        const float* x = (k < 9216) ? (p.As + k) : (p.Bs + (k - 9216));
#pragma unroll
        for (int b = 0; b < NB; ++b) acc[b] = fmaf(x[b * 9216], w, acc[b]);
      }
#pragma unroll
      for (int b = 0; b < NB; ++b)
        p.partT[(size_t)(kc * NB + b) * NTF + j] = acc[b];
    } else if (u < 640) {               // pfeat partial
      const int t = u - 576;
      const int j = (t & 1) * 256 + tid;
      const int kc = t >> 1;
      const int kbase = kc * 128;
      float acc[NB] = {};
      for (int kk = 0; kk < 128; ++kk) {
        const int k = kbase + kk;
        const float w = p.W_cp[(size_t)k * NPF + j];
#pragma unroll
        for (int b = 0; b < NB; ++b) acc[b] = fmaf(p.prompt[b * KP + k], w, acc[b]);
      }
#pragma unroll
      for (int b = 0; b < NB; ++b)
        p.partP[(size_t)(kc * NB + b) * NPF + j] = acc[b];
    } else if (u < 704) {               // L_A / L_B (split-K halves)
      const int t = u - 640;
      const bool isA = t < 32;
      const int tt = isA ? t : t - 32;
      const int dc = tt & 15;
      const int kh = tt >> 4;
      const float* W = (isA ? p.W_A : p.W_B) + (size_t)(NFUSED + kh * 128) * ND;
      float* pL = (isA ? p.pLA : p.pLB) + (size_t)kh * NL * ND;
      const int d = dc * 256 + tid;
      float acc[NL] = {};
      for (int kk = 0; kk < 128; ++kk) {
        const float w = W[(size_t)kk * ND + d];
        const float* el = p.E_layer + kh * 128 + kk;
#pragma unroll
        for (int l = 0; l < NL; ++l) acc[l] = fmaf(el[l * 256], w, acc[l]);
      }
#pragma unroll
      for (int l = 0; l < NL; ++l) pL[(size_t)l * ND + d] = acc[l];
    } else {                            // C_A / C_BT
      const int t = u - 704;
      const bool isA = t < 16;
      const int tt = isA ? t : t - 16;
      const float* W = (isA ? p.W_A : p.W_B) + (size_t)(NFUSED + 256) * ND;
      __syncthreads();
      for (int i = tid; i < NR * 64; i += 256) smem[i] = p.E_chunk[i];
      __syncthreads();
      const int d = tt * 256 + tid;
      float w[64];
#pragma unroll
      for (int k = 0; k < 64; ++k) w[k] = W[(size_t)k * ND + d];
      for (int r = 0; r < NR; ++r) {
        float s = 0.f;
#pragma unroll
        for (int k = 0; k < 64; ++k) s = fmaf(smem[r * 64 + k], w[k], s);
        if (isA) p.CA[(size_t)r * ND + d] = s;
        else     p.CBT[(size_t)d * NR + r] = s;
      }
    }
  }
  grid.sync();

  // ---------------- Phase 2: fused reduce (48 units) --------------------
  for (int u = bid; u < 48; u += G) {
    if (u < 32) {
      const int idx = u * 256 + tid;
      const int b = idx >> 10, j = idx & 1023;
      float s = p.b_ct[j];
      for (int kc = 0; kc < TKC; ++kc) s += p.partT[(size_t)(kc * NB + b) * NTF + j];
      p.fused[b * NFUSED + j] = fmaxf(s, 0.f);
    } else {
      const int idx = (u - 32) * 256 + tid;
      const int b = idx >> 9, j = idx & 511;
      float s = p.b_cp[j];
      for (int kc = 0; kc < PKC; ++kc) s += p.partP[(size_t)(kc * NB + b) * NPF + j];
      p.fused[b * NFUSED + NTF + j] = fmaxf(s, 0.f);
    }
  }
  grid.sync();

  // ---------------- Phase 3: F partials + gate (576 units) --------------
  for (int u = bid; u < 576; u += G) {
    if (u < 384) {
      const bool isA = u < 192;
      const int t = isA ? u : u - 192;
      const float* W = isA ? p.W_A : p.W_B;
      float* part = isA ? p.pFA : p.pFB;
      const int d = (t & 15) * 256 + tid;
      const int kc = t >> 4;
      const int kbase = kc * 128;
      float acc[NB] = {};
      for (int kk = 0; kk < 128; ++kk) {
        const int k = kbase + kk;
        const float w = W[(size_t)k * ND + d];
#pragma unroll
        for (int b = 0; b < NB; ++b) acc[b] = fmaf(p.fused[b * NFUSED + k], w, acc[b]);
      }
#pragma unroll
      for (int b = 0; b < NB; ++b)
        part[(size_t)(kc * NB + b) * ND + d] = acc[b];
    } else {
      const int bl = u - 384;
      const int b = bl / NL, l = bl % NL;
      float s = 0.f;
      for (int k = tid; k < NFUSED; k += 256)
        s = fmaf(p.fused[b * NFUSED + k], p.W_pc[k * NL + l], s);
      __syncthreads();
      smem[tid] = s;
      __syncthreads();
#pragma unroll
      for (int off = 128; off > 0; off >>= 1) {
        if (tid < off) smem[tid] += smem[tid + off];
        __syncthreads();
      }
      if (tid == 0) {
        const float g = (smem[0] + p.b_pc[l]) > 0.f ? 1.f : 0.f;
        p.gatew[bl] = g;
        p.outG[bl] = g;
      }
    }
  }
  grid.sync();

  // ---------------- Phase 4: writers (3072 units) -----------------------
  for (int u = bid; u < 3072; u += G) {
    if (u < 1536) {                     // A writer
      const int bl = u >> 3;
      const int rest = u & 7;
      const int b = bl / NL, l = bl % NL;
      const int d = (rest >> 1) * 1024 + tid * 4;
      const int r0 = (rest & 1) * 32;
      const float g = p.gatew[bl];
      v4f base = *(const v4f*)(p.b_A + d);
#pragma unroll
      for (int kc = 0; kc < FKC; ++kc)
        base += *(const v4f*)(p.pFA + (size_t)(kc * NB + b) * ND + d);
      base += *(const v4f*)(p.pLA + (size_t)l * ND + d);
      base += *(const v4f*)(p.pLA + (size_t)(NL + l) * ND + d);
      float* outp = p.outA + ((size_t)bl * NR + r0) * ND + d;
#pragma unroll 4
      for (int r = 0; r < 32; ++r) {
        const v4f c = *(const v4f*)(p.CA + (size_t)(r0 + r) * ND + d);
        const v4f v = (base + c) * g;
        __builtin_nontemporal_store(v, (v4f*)outp);
        outp += ND;
      }
    } else {                            // B writer
      const int t = u - 1536;
      const int bl = t >> 3;
      const int b = bl / NL, l = bl % NL;
      const int dbase = (t & 7) * 512;
      __syncthreads();
      for (int dd = tid; dd < 512; dd += 256) {
        const int d = dbase + dd;
        float s = p.b_B[d] + p.pLB[(size_t)l * ND + d] + p.pLB[(size_t)(NL + l) * ND + d];
#pragma unroll
        for (int kc = 0; kc < FKC; ++kc)
          s += p.pFB[(size_t)(kc * NB + b) * ND + d];
        smem[dd] = s;
      }
      __syncthreads();
      const int dd16 = tid >> 4;
      const int r4 = (tid & 15) * 4;
#pragma unroll 4
      for (int i = 0; i < 32; ++i) {
        const int dloc = i * 16 + dd16;
        const int d = dbase + dloc;
        const v4f c = *(const v4f*)(p.CBT + (size_t)d * NR + r4);
        const v4f v = c + smem[dloc];
        __builtin_nontemporal_store(v, (v4f*)(p.outB + ((size_t)bl * ND + d) * NR + r4));
      }
    }
  }
}

extern "C" void kernel_launch(void* const* d_in, const int* in_sizes, int n_in,
                              void* d_out, int out_size, void* d_ws, size_t ws_size,
                              hipStream_t stream) {
  float* ws = (float*)d_ws;
  float* outA = (float*)d_out;                       // [192,64,4096]
  float* outB = outA + (size_t)192 * NR * ND;        // [192,4096,64]
  float* outG = outB + (size_t)192 * ND * NR;        // [192]

  KParams p;
  p.As      = (const float*)d_in[0];
  p.Bs      = (const float*)d_in[1];
  p.prompt  = (const float*)d_in[2];
  p.W_ct    = (const float*)d_in[3];
  p.b_ct    = (const float*)d_in[4];
  p.W_cp    = (const float*)d_in[5];
  p.b_cp    = (const float*)d_in[6];
  p.W_pc    = (const float*)d_in[7];
  p.b_pc    = (const float*)d_in[8];
  p.E_layer = (const float*)d_in[9];
  p.E_chunk = (const float*)d_in[10];
  p.W_A     = (const float*)d_in[11];
  p.b_A     = (const float*)d_in[12];
  p.W_B     = (const float*)d_in[13];
  p.b_B     = (const float*)d_in[14];
  p.fused   = ws + WS_FUSED;
  p.gatew   = ws + WS_GATE;
  p.pLA     = ws + WS_PLA;
  p.pLB     = ws + WS_PLB;
  p.CA      = ws + WS_CA;
  p.CBT     = ws + WS_CBT;
  p.partT   = ws + WS_PT;
  p.partP   = ws + WS_PP;
  p.pFA     = ws + WS_PFA;
  p.pFB     = ws + WS_PFB;
  p.outA    = outA;
  p.outB    = outB;
  p.outG    = outG;

  int maxb = 0;
  (void)hipOccupancyMaxActiveBlocksPerMultiprocessor(
      &maxb, reinterpret_cast<const void*>(k_all), 256, 0);
  if (maxb < 1) maxb = 1;
  long grid = (long)maxb * 256;
  if (grid > 1024) grid = 1024;

  void* args[] = {&p};
  (void)hipLaunchCooperativeKernel(reinterpret_cast<const void*>(k_all),
                                   dim3((int)grid), dim3(256), args, 0, stream);
}

// Round 5
// 166.870 us; speedup vs baseline: 3.1246x; 3.1246x over previous
//
#include <hip/hip_runtime.h>

typedef float v4f __attribute__((ext_vector_type(4)));

#define NB 8        // batch
#define NL 24       // layers
#define NR 64       // chunks
#define ND 4096     // DL
#define NFUSED 1536
#define NTF 1024
#define NPF 512
#define KP 4096     // DP

// split-K chunking
#define TKC 144     // tfeat k-chunks of 128
#define PKC 32      // pfeat k-chunks of 128
#define FKC 12      // F k-chunks of 128

// workspace float offsets
#define WS_GATE  12288      // 192                -> 12480
#define WS_PLA   12480      // 2*24*4096 = 196608 -> 209088
#define WS_PLB   209088     // 196608             -> 405696
#define WS_CA    405696     // 262144             -> 667840
#define WS_CBT   667840     // 262144             -> 929984
#define WS_PT    929984     // 144*8*1024=1179648 -> 2109632
#define WS_PP    2109632    // 32*8*512 = 131072  -> 2240704
#define WS_PFA   2240704    // 12*8*4096= 393216  -> 2633920
#define WS_PFB   2633920    // 393216             -> 3027136

// =====================================================================
// K1: everything independent of `fused` — 736 blocks, ~128KB read each.
//   [0,576)   tfeat partials   (4 j-chunks x 144 k-chunks of 128)
//   [576,640) pfeat partials   (2 j-chunks x 32 k-chunks of 128)
//   [640,704) L_A / L_B        (16 d-chunks x 2 k-halves x 2 mats)
//   [704,736) C_A / C_BT       (16 d-chunks x 2 mats)
// =====================================================================
__global__ __launch_bounds__(256) void k_indep(
    const float* __restrict__ As, const float* __restrict__ Bs,
    const float* __restrict__ W_ct,
    const float* __restrict__ prompt, const float* __restrict__ W_cp,
    const float* __restrict__ E_layer, const float* __restrict__ E_chunk,
    const float* __restrict__ W_A, const float* __restrict__ W_B,
    float* __restrict__ partT, float* __restrict__ partP,
    float* __restrict__ pLA, float* __restrict__ pLB,
    float* __restrict__ CA, float* __restrict__ CBT) {
  __shared__ float e[NR * 64];
  const int bx = blockIdx.x;
  const int tid = threadIdx.x;

  if (bx < 576) {                       // ---- tfeat partial (k-chunk 128)
    const int j = (bx & 3) * 256 + tid;
    const int kc = bx >> 2;
    const int kbase = kc * 128;
    float acc[NB] = {};
    for (int kk = 0; kk < 128; ++kk) {
      const int k = kbase + kk;
      const float w = W_ct[(size_t)k * NTF + j];
      const float* x = (k < 9216) ? (As + k) : (Bs + (k - 9216));
#pragma unroll
      for (int b = 0; b < NB; ++b) acc[b] = fmaf(x[b * 9216], w, acc[b]);
    }
#pragma unroll
    for (int b = 0; b < NB; ++b)
      partT[(size_t)(kc * NB + b) * NTF + j] = acc[b];
  } else if (bx < 640) {                // ---- pfeat partial (k-chunk 128)
    const int t = bx - 576;
    const int j = (t & 1) * 256 + tid;
    const int kc = t >> 1;
    const int kbase = kc * 128;
    float acc[NB] = {};
    for (int kk = 0; kk < 128; ++kk) {
      const int k = kbase + kk;
      const float w = W_cp[(size_t)k * NPF + j];
#pragma unroll
      for (int b = 0; b < NB; ++b) acc[b] = fmaf(prompt[b * KP + k], w, acc[b]);
    }
#pragma unroll
    for (int b = 0; b < NB; ++b)
      partP[(size_t)(kc * NB + b) * NPF + j] = acc[b];
  } else if (bx < 704) {                // ---- L_A / L_B (split-K 2 halves)
    const int t = bx - 640;
    const bool isA = t < 32;
    const int tt = isA ? t : t - 32;
    const int dc = tt & 15;
    const int kh = tt >> 4;             // 0 or 1
    const float* W = (isA ? W_A : W_B) + (size_t)(NFUSED + kh * 128) * ND;
    float* pL = (isA ? pLA : pLB) + (size_t)kh * NL * ND;
    const int d = dc * 256 + tid;
    float acc[NL] = {};
    for (int kk = 0; kk < 128; ++kk) {
      const float w = W[(size_t)kk * ND + d];
      const float* el = E_layer + kh * 128 + kk;
#pragma unroll
      for (int l = 0; l < NL; ++l) acc[l] = fmaf(el[l * 256], w, acc[l]);
    }
#pragma unroll
    for (int l = 0; l < NL; ++l) pL[(size_t)l * ND + d] = acc[l];
  } else {                              // ---- C_A / C_BT
    const int t = bx - 704;
    const bool isA = t < 16;
    const int tt = isA ? t : t - 16;
    const float* W = (isA ? W_A : W_B) + (size_t)(NFUSED + 256) * ND;
    for (int i = tid; i < NR * 64; i += 256) e[i] = E_chunk[i];
    __syncthreads();
    const int d = tt * 256 + tid;
    float w[64];
#pragma unroll
    for (int k = 0; k < 64; ++k) w[k] = W[(size_t)k * ND + d];
    for (int r = 0; r < NR; ++r) {
      float s = 0.f;
#pragma unroll
      for (int k = 0; k < 64; ++k) s = fmaf(e[r * 64 + k], w[k], s);
      if (isA) CA[(size_t)r * ND + d] = s;
      else     CBT[(size_t)d * NR + r] = s;
    }
  }
}

// =====================================================================
// K3': F partials + gate — 392 blocks. Each block recomputes the fused
// slice it needs from the (L2-resident) partT/partP, removing the K2
// kernel boundary.
//   [0,192)   F_A partial (dc = t&15, kc = t>>4)
//   [192,384) F_B partial
//   [384,392) gate, one batch b per block
// =====================================================================
__global__ __launch_bounds__(256) void k_dep(
    const float* __restrict__ partT, const float* __restrict__ partP,
    const float* __restrict__ b_ct, const float* __restrict__ b_cp,
    const float* __restrict__ W_A, const float* __restrict__ W_B,
    const float* __restrict__ W_pc, const float* __restrict__ b_pc,
    float* __restrict__ pFA, float* __restrict__ pFB,
    float* __restrict__ gate_ws, float* __restrict__ gate_out) {
  __shared__ float smem[1664];   // F: 8x128 fused slice; gate: 1536 + 96
  const int bx = blockIdx.x;
  const int tid = threadIdx.x;

  if (bx < 384) {                       // ---- F partial
    const bool isA = bx < 192;
    const int t = isA ? bx : bx - 192;
    const float* W = isA ? W_A : W_B;
    float* part = isA ? pFA : pFB;
    const int dc = t & 15;
    const int kc = t >> 4;

    // stage 1: fused slice [8][128] for k in [kc*128, kc*128+128)
    const int j = tid & 127;
    const int bhalf = tid >> 7;         // 0/1
    if (kc < 8) {
      const int gj = kc * 128 + j;
      const float bias = b_ct[gj];
#pragma unroll
      for (int p4 = 0; p4 < 4; ++p4) {
        const int b = p4 * 2 + bhalf;
        float s = bias;
        for (int kcc = 0; kcc < TKC; ++kcc)
          s += partT[(size_t)(kcc * NB + b) * NTF + gj];
        smem[b * 128 + j] = fmaxf(s, 0.f);
      }
    } else {
      const int jj = kc * 128 - NTF + j;
      const float bias = b_cp[jj];
#pragma unroll
      for (int p4 = 0; p4 < 4; ++p4) {
        const int b = p4 * 2 + bhalf;
        float s = bias;
        for (int kcc = 0; kcc < PKC; ++kcc)
          s += partP[(size_t)(kcc * NB + b) * NPF + jj];
        smem[b * 128 + j] = fmaxf(s, 0.f);
      }
    }
    __syncthreads();

    // stage 2: partial GEMM for this k-chunk
    const int d = dc * 256 + tid;
    float acc[NB] = {};
    for (int kk = 0; kk < 128; ++kk) {
      const float w = W[(size_t)(kc * 128 + kk) * ND + d];
#pragma unroll
      for (int b = 0; b < NB; ++b) acc[b] = fmaf(smem[b * 128 + kk], w, acc[b]);
    }
#pragma unroll
    for (int b = 0; b < NB; ++b)
      part[(size_t)(kc * NB + b) * ND + d] = acc[b];
  } else {                              // ---- gate for batch b
    const int b = bx - 384;
    for (int j = tid; j < NFUSED; j += 256) {
      float s;
      if (j < NTF) {
        s = b_ct[j];
        for (int kc = 0; kc < TKC; ++kc)
          s += partT[(size_t)(kc * NB + b) * NTF + j];
      } else {
        const int jj = j - NTF;
        s = b_cp[jj];
        for (int kc = 0; kc < PKC; ++kc)
          s += partP[(size_t)(kc * NB + b) * NPF + jj];
      }
      smem[j] = fmaxf(s, 0.f);
    }
    __syncthreads();
    float acc[NL] = {};
    for (int j = tid; j < NFUSED; j += 256) {
      const float f = smem[j];
#pragma unroll
      for (int l = 0; l < NL; ++l) acc[l] = fmaf(f, W_pc[j * NL + l], acc[l]);
    }
#pragma unroll
    for (int off = 32; off > 0; off >>= 1)
#pragma unroll
      for (int l = 0; l < NL; ++l) acc[l] += __shfl_down(acc[l], off);
    const int wave = tid >> 6, lane = tid & 63;
    if (lane == 0)
#pragma unroll
      for (int l = 0; l < NL; ++l) smem[NFUSED + wave * NL + l] = acc[l];
    __syncthreads();
    if (tid < NL) {
      float s = b_pc[tid];
#pragma unroll
      for (int w = 0; w < 4; ++w) s += smem[NFUSED + w * NL + tid];
      const float g = s > 0.f ? 1.f : 0.f;
      gate_ws[b * NL + tid] = g;
      gate_out[b * NL + tid] = g;
    }
  }
}

// =====================================================================
// K4: writers (F-reduce + L-reduce folded in) — 3072 blocks
//   [0,1536)    A_large: bl = t>>3, dchunk = (t&7)>>1, rchunk = t&1
//   [1536,3072) B_large: bl = t>>3, dchunk = t&7
// =====================================================================
__global__ __launch_bounds__(256) void k_out(
    const float* __restrict__ pFA, const float* __restrict__ pFB,
    const float* __restrict__ b_A, const float* __restrict__ b_B,
    const float* __restrict__ pLA, const float* __restrict__ pLB,
    const float* __restrict__ CA, const float* __restrict__ CBT,
    const float* __restrict__ gate,
    float* __restrict__ outA, float* __restrict__ outB) {
  __shared__ float sbase[512];
  const int bx = blockIdx.x;
  const int tid = threadIdx.x;
  if (bx < 1536) {                      // ---- A writer
    const int bl = bx >> 3;
    const int rest = bx & 7;
    const int b = bl / NL, l = bl % NL;
    const int d = (rest >> 1) * 1024 + tid * 4;
    const int r0 = (rest & 1) * 32;
    const float g = gate[bl];
    v4f base = *(const v4f*)(b_A + d);
#pragma unroll
    for (int kc = 0; kc < FKC; ++kc)
      base += *(const v4f*)(pFA + (size_t)(kc * NB + b) * ND + d);
    base += *(const v4f*)(pLA + (size_t)l * ND + d);
    base += *(const v4f*)(pLA + (size_t)(NL + l) * ND + d);
    float* outp = outA + ((size_t)bl * NR + r0) * ND + d;
#pragma unroll 4
    for (int r = 0; r < 32; ++r) {
      const v4f c = *(const v4f*)(CA + (size_t)(r0 + r) * ND + d);
      const v4f v = (base + c) * g;
      __builtin_nontemporal_store(v, (v4f*)outp);
      outp += ND;
    }
  } else {                              // ---- B writer
    const int t = bx - 1536;
    const int bl = t >> 3;
    const int b = bl / NL, l = bl % NL;
    const int dbase = (t & 7) * 512;
    for (int dd = tid; dd < 512; dd += 256) {
      const int d = dbase + dd;
      float s = b_B[d] + pLB[(size_t)l * ND + d] + pLB[(size_t)(NL + l) * ND + d];
#pragma unroll
      for (int kc = 0; kc < FKC; ++kc)
        s += pFB[(size_t)(kc * NB + b) * ND + d];
      sbase[dd] = s;
    }
    __syncthreads();
    const int dd16 = tid >> 4;
    const int r4 = (tid & 15) * 4;
#pragma unroll 4
    for (int i = 0; i < 32; ++i) {
      const int dloc = i * 16 + dd16;
      const int d = dbase + dloc;
      const v4f c = *(const v4f*)(CBT + (size_t)d * NR + r4);
      const v4f v = c + sbase[dloc];
      __builtin_nontemporal_store(v, (v4f*)(outB + ((size_t)bl * ND + d) * NR + r4));
    }
  }
}

extern "C" void kernel_launch(void* const* d_in, const int* in_sizes, int n_in,
                              void* d_out, int out_size, void* d_ws, size_t ws_size,
                              hipStream_t stream) {
  const float* A_small   = (const float*)d_in[0];
  const float* B_small   = (const float*)d_in[1];
  const float* prompt    = (const float*)d_in[2];
  const float* W_ct      = (const float*)d_in[3];
  const float* b_ct      = (const float*)d_in[4];
  const float* W_cp      = (const float*)d_in[5];
  const float* b_cp      = (const float*)d_in[6];
  const float* W_pc      = (const float*)d_in[7];
  const float* b_pc      = (const float*)d_in[8];
  const float* E_layer   = (const float*)d_in[9];
  const float* E_chunk   = (const float*)d_in[10];
  const float* W_A       = (const float*)d_in[11];
  const float* b_A       = (const float*)d_in[12];
  const float* W_B       = (const float*)d_in[13];
  const float* b_B       = (const float*)d_in[14];

  float* ws    = (float*)d_ws;
  float* gatew = ws + WS_GATE;
  float* pLA   = ws + WS_PLA;
  float* pLB   = ws + WS_PLB;
  float* CA    = ws + WS_CA;
  float* CBT   = ws + WS_CBT;
  float* partT = ws + WS_PT;
  float* partP = ws + WS_PP;
  float* pFA   = ws + WS_PFA;
  float* pFB   = ws + WS_PFB;

  float* outA = (float*)d_out;                       // [192,64,4096]
  float* outB = outA + (size_t)192 * NR * ND;        // [192,4096,64]
  float* outG = outB + (size_t)192 * ND * NR;        // [192]

  k_indep<<<736, 256, 0, stream>>>(A_small, B_small, W_ct, prompt, W_cp,
                                   E_layer, E_chunk, W_A, W_B,
                                   partT, partP, pLA, pLB, CA, CBT);
  k_dep<<<392, 256, 0, stream>>>(partT, partP, b_ct, b_cp, W_A, W_B,
                                 W_pc, b_pc, pFA, pFB, gatew, outG);
  k_out<<<3072, 256, 0, stream>>>(pFA, pFB, b_A, b_B, pLA, pLB, CA, CBT,
                                  gatew, outA, outB);
}